// Round 1
// baseline (14809.471 us; speedup 1.0000x reference)
//
#include <hip/hip_runtime.h>

// Tanh RNN: B=64, S=2048, I=512, H=512, fp32 in/out.
// Phase 0 (prep): cast w_ih, w_hh, state -> fp16; bias = b_ih + b_hh.
// Phase 1 (xproj): xp[s*64+b][h] = sum_i inputs[b][s][i]*w_ih[h][i] + bias[h]  (f16 MFMA, fp32 out)
// Phase 2 (rnn):  h_t = tanh(xp_t + h_{t-1} @ w_hh^T), 16 persistent WGs,
//                 w_hh fragments register-resident, h exchanged via global fp16
//                 ping-pong buffers + per-row-group flag counters.

typedef _Float16 half8 __attribute__((ext_vector_type(8)));
typedef _Float16 half4 __attribute__((ext_vector_type(4)));
typedef float f32x4 __attribute__((ext_vector_type(4)));

#define B_SZ 64
#define S_SZ 2048
#define I_SZ 512
#define H_SZ 512
#define OUT1_OFF 67108864ull  // S*B*H

// workspace offsets (bytes)
#define XP_OFF    0ull                  // 268435456 B (S*B*H fp32)
#define WIH_OFF   268435456ull          // 524288 B
#define WHH_OFF   268959744ull          // 524288 B
#define BIAS_OFF  269484032ull          // 2048 B
#define H0_OFF    269486080ull          // 65536 B
#define H1_OFF    269551616ull          // 65536 B
#define FLAGS_OFF 269617152ull          // 32768 B (2048 steps * 4 row-groups * u32)

__global__ void prep_kernel(const float* __restrict__ wih, const float* __restrict__ whh,
                            const float* __restrict__ bih, const float* __restrict__ bhh,
                            const float* __restrict__ state,
                            _Float16* __restrict__ wih16, _Float16* __restrict__ whh16,
                            float* __restrict__ bias, _Float16* __restrict__ h0)
{
    const int i = blockIdx.x * 256 + threadIdx.x;   // grid 1024*256 == 262144
    if (i < 262144) {
        wih16[i] = (_Float16)wih[i];
        whh16[i] = (_Float16)whh[i];
    }
    if (i < 512)   bias[i] = bih[i] + bhh[i];
    if (i < 32768) h0[i] = (_Float16)state[i];
}

// ---------------- Phase 1: input projection GEMM ----------------
// One block per s. Block = 512 threads (8 waves). Output tile 64 rows x 512 cols.
// A = inputs[b][s][:] (64 rows, staged fp32->fp16 in LDS, XOR-swizzled),
// B = w_ih fp16 (row-major, read from L2).
__global__ __launch_bounds__(512, 1) void xproj_kernel(
    const float* __restrict__ inputs, const _Float16* __restrict__ wih16,
    const float* __restrict__ bias, float* __restrict__ xp)
{
    __shared__ _Float16 Alds[64 * 512];  // 64 KiB
    const int s = blockIdx.x;

    // stage: 64 rows x 512 f32 -> f16 LDS, swizzle byte-cols by ((row&7)<<4)
    for (int idx = threadIdx.x; idx < 64 * 128; idx += 512) {
        const int row = idx >> 7, chunk = idx & 127;
        const float4 v = *reinterpret_cast<const float4*>(
            inputs + ((size_t)row * S_SZ + s) * I_SZ + chunk * 4);
        half4 hv;
        hv[0] = (_Float16)v.x; hv[1] = (_Float16)v.y;
        hv[2] = (_Float16)v.z; hv[3] = (_Float16)v.w;
        const int bc = (chunk * 8) ^ ((row & 7) << 4);
        *reinterpret_cast<half4*>(reinterpret_cast<char*>(Alds) + row * 1024 + bc) = hv;
    }
    __syncthreads();

    const int lane = threadIdx.x & 63, w = threadIdx.x >> 6;
    const int l15 = lane & 15, lg = lane >> 4;

    f32x4 acc[4][4];
    #pragma unroll
    for (int m = 0; m < 4; ++m)
        #pragma unroll
        for (int n = 0; n < 4; ++n)
            acc[m][n] = 0.0f;

    for (int kk = 0; kk < 16; ++kk) {
        half8 af[4], bf[4];
        #pragma unroll
        for (int m = 0; m < 4; ++m) {
            const int row = m * 16 + l15;
            const int bc = (kk * 64 + lg * 16) ^ ((row & 7) << 4);
            af[m] = *reinterpret_cast<const half8*>(
                reinterpret_cast<const char*>(Alds) + row * 1024 + bc);
        }
        #pragma unroll
        for (int n = 0; n < 4; ++n) {
            const int col = w * 64 + n * 16 + l15;
            bf[n] = *reinterpret_cast<const half8*>(wih16 + (size_t)col * 512 + kk * 32 + lg * 8);
        }
        #pragma unroll
        for (int m = 0; m < 4; ++m)
            #pragma unroll
            for (int n = 0; n < 4; ++n)
                acc[m][n] = __builtin_amdgcn_mfma_f32_16x16x32_f16(af[m], bf[n], acc[m][n], 0, 0, 0);
    }

    #pragma unroll
    for (int m = 0; m < 4; ++m) {
        #pragma unroll
        for (int n = 0; n < 4; ++n) {
            const int gcol = w * 64 + n * 16 + l15;
            const float bv = bias[gcol];
            #pragma unroll
            for (int q = 0; q < 4; ++q) {
                const int grow = m * 16 + lg * 4 + q;
                xp[((size_t)s * 64 + grow) * 512 + gcol] = acc[m][n][q] + bv;
            }
        }
    }
}

// ---------------- Phase 2: persistent recurrence ----------------
// Grid = 16 WGs: (row-group r in 0..3 of 16 batch rows) x (col-slice c in 0..3 of 128 cols).
// 4 waves/WG, wave w owns 32 cols (2 MFMA N-tiles). w_hh fragments live in VGPRs
// for all 2048 steps. h ping-pongs between two global fp16 buffers; sync is a
// per-(step,row-group) u32 counter (4 producers each).
__global__ __launch_bounds__(256, 1) void rnn_step_kernel(
    const _Float16* __restrict__ whh16, const float* __restrict__ xp,
    _Float16* __restrict__ hbuf0, _Float16* __restrict__ hbuf1,
    float* __restrict__ out, unsigned int* __restrict__ flags)
{
    const int r = blockIdx.x >> 2, c = blockIdx.x & 3;
    const int lane = threadIdx.x & 63, w = threadIdx.x >> 6;
    const int l15 = lane & 15, lg = lane >> 4;
    const int colbase = c * 128 + w * 32;

    // register-resident w_hh fragments: B[k][j] = whh[j][k], lane l15 = j
    half8 wf[2][16];
    #pragma unroll
    for (int n = 0; n < 2; ++n) {
        const int col = colbase + n * 16 + l15;
        #pragma unroll
        for (int kk = 0; kk < 16; ++kk)
            wf[n][kk] = *reinterpret_cast<const half8*>(whh16 + (size_t)col * 512 + kk * 32 + lg * 8);
    }

    const int rowb = r * 16 + lg * 4;  // C/D: row = (lane>>4)*4 + q
    const int hrow = r * 16 + l15;     // A: row = lane&15

    for (int t = 0; t < S_SZ; ++t) {
        // prefetch xp for this step (independent of the flag wait -> hides HBM latency)
        float xpv[2][4];
        #pragma unroll
        for (int n = 0; n < 2; ++n)
            #pragma unroll
            for (int q = 0; q < 4; ++q)
                xpv[n][q] = xp[((size_t)t * 64 + rowb + q) * 512 + colbase + n * 16 + l15];

        if (t > 0) {
            if (threadIdx.x == 0) {
                long guard = 0;
                while (__hip_atomic_load(&flags[(t - 1) * 4 + r], __ATOMIC_RELAXED,
                                         __HIP_MEMORY_SCOPE_AGENT) < 4u) {
                    __builtin_amdgcn_s_sleep(1);
                    if (++guard > 100000000L) break;  // anti-hang escape
                }
            }
            __syncthreads();
            __threadfence();  // acquire: invalidate stale cached h lines
        }

        const _Float16* __restrict__ hsrc = (t & 1) ? hbuf1 : hbuf0;
        _Float16* __restrict__ hdst = (t & 1) ? hbuf0 : hbuf1;

        half8 af[16];
        #pragma unroll
        for (int kk = 0; kk < 16; ++kk)
            af[kk] = *reinterpret_cast<const half8*>(hsrc + hrow * 512 + kk * 32 + lg * 8);

        f32x4 acc[2];
        acc[0] = 0.0f; acc[1] = 0.0f;
        #pragma unroll
        for (int kk = 0; kk < 16; ++kk) {
            acc[0] = __builtin_amdgcn_mfma_f32_16x16x32_f16(af[kk], wf[0][kk], acc[0], 0, 0, 0);
            acc[1] = __builtin_amdgcn_mfma_f32_16x16x32_f16(af[kk], wf[1][kk], acc[1], 0, 0, 0);
        }

        #pragma unroll
        for (int n = 0; n < 2; ++n) {
            const int gcol = colbase + n * 16 + l15;
            #pragma unroll
            for (int q = 0; q < 4; ++q) {
                const int grow = rowb + q;
                const float hv = tanhf(acc[n][q] + xpv[n][q]);
                out[((size_t)t * 64 + grow) * 512 + gcol] = hv;
                hdst[grow * 512 + gcol] = (_Float16)hv;
                if (t == S_SZ - 1)
                    out[OUT1_OFF + (size_t)gcol * 64 + grow] = hv;  // h_last^T [H,B]
            }
        }

        __threadfence();   // release: make h stores agent-visible
        __syncthreads();
        if (threadIdx.x == 0)
            __hip_atomic_fetch_add(&flags[t * 4 + r], 1u, __ATOMIC_RELEASE,
                                   __HIP_MEMORY_SCOPE_AGENT);
    }
}

extern "C" void kernel_launch(void* const* d_in, const int* in_sizes, int n_in,
                              void* d_out, int out_size, void* d_ws, size_t ws_size,
                              hipStream_t stream)
{
    const float* inputs = (const float*)d_in[0];
    const float* state  = (const float*)d_in[1];
    const float* w_ih   = (const float*)d_in[2];
    const float* b_ih   = (const float*)d_in[3];
    const float* w_hh   = (const float*)d_in[4];
    const float* b_hh   = (const float*)d_in[5];
    float* out = (float*)d_out;
    char* ws = (char*)d_ws;

    float*        xp     = (float*)(ws + XP_OFF);
    _Float16*     wih16  = (_Float16*)(ws + WIH_OFF);
    _Float16*     whh16  = (_Float16*)(ws + WHH_OFF);
    float*        bias   = (float*)(ws + BIAS_OFF);
    _Float16*     h0     = (_Float16*)(ws + H0_OFF);
    _Float16*     h1     = (_Float16*)(ws + H1_OFF);
    unsigned int* flags  = (unsigned int*)(ws + FLAGS_OFF);

    hipMemsetAsync(flags, 0, 32768, stream);  // flag counters must start at 0 every call
    prep_kernel<<<1024, 256, 0, stream>>>(w_ih, w_hh, b_ih, b_hh, state, wih16, whh16, bias, h0);
    xproj_kernel<<<S_SZ, 512, 0, stream>>>(inputs, wih16, bias, xp);
    rnn_step_kernel<<<16, 256, 0, stream>>>(whh16, xp, h0, h1, out, flags);
}